// Round 10
// baseline (892.926 us; speedup 1.0000x reference)
//
#include <hip/hip_runtime.h>

// ---------------------------------------------------------------------------
// YOLOv2 head on MI355X (gfx950).
// conv1 3x3 (512->1024) + BN + leaky -> conv2 1x1 (1024->425) + bias -> decode
// fp16 3-term split GEMM (ah*bh + ah*bl + al*bh) for fp32-class accuracy.
// R10 = R9 + XCD-aware block swizzle on gemm1 (T1):
//   flat grid 512; x=bid&7 (XCD), j=bid>>3; mt=x>>1, nt=(x&1)*64+j.
//   64 blocks per XCD share one A-panel + contiguous nt range -> A K-slices
//   L2-hit instead of HBM re-fetch (FETCH 664 MB -> expect <300 MB).
// ---------------------------------------------------------------------------

typedef _Float16 f16;
typedef _Float16 f16x8 __attribute__((ext_vector_type(8)));
typedef _Float16 f16x4v __attribute__((ext_vector_type(4)));
typedef float    f32x4 __attribute__((ext_vector_type(4)));

__device__ __forceinline__ void gload16(const f16* g, f16* l) {
  __builtin_amdgcn_global_load_lds(
      (const __attribute__((address_space(1))) void*)g,
      (__attribute__((address_space(3))) void*)l, 16, 0, 0);
}

#define MFMA(a, b, c) __builtin_amdgcn_mfma_f32_16x16x32_f16(a, b, c, 0, 0, 0)
#define ASM_VMCNT(N) asm volatile("s_waitcnt vmcnt(" #N ")" ::: "memory")
#define SBAR()                           \
  {                                      \
    __builtin_amdgcn_s_barrier();        \
    __builtin_amdgcn_sched_barrier(0);   \
  }

// LDS region bases (f16 elements): each region 2 bufs x 16 units x 512
#define R_AH 0
#define R_AL 16384
#define R_BH 32768
#define R_BL 49152

// anchors
__device__ const float c_AW[5] = {42.f, 98.f, 180.f, 300.f, 400.f};
__device__ const float c_AH_[5] = {45.f, 130.f, 260.f, 180.f, 400.f};

// ---------------------------------------------------------------------------
__global__ void prep_misc(const float* __restrict__ g, const float* __restrict__ be,
                          const float* __restrict__ mn, const float* __restrict__ vr,
                          const float* __restrict__ b2,
                          float* __restrict__ scale, float* __restrict__ shift,
                          float* __restrict__ bias) {
  int i = threadIdx.x;  // 1024 threads
  float s = g[i] / sqrtf(vr[i] + 1e-5f);
  shift[i] = be[i] - mn[i] * s;
  scale[i] = s * (1.0f / 1024.0f);
  if (i < 512) bias[i] = (i < 425) ? b2[i] : 0.f;
}

__global__ __launch_bounds__(256) void prep_w1(const float* __restrict__ w,
                                               f16* __restrict__ Ah, f16* __restrict__ Al) {
  const int co = blockIdx.x;
  const int k = blockIdx.y * 256 + threadIdx.x;  // < 4608
  const int ky = k / 1536, rem = k - ky * 1536;
  const int kx = rem >> 9, ci = rem & 511;
  float v = w[((co * 512 + ci) * 3 + ky) * 3 + kx] * 1024.f;
  f16 h = (f16)v;
  Ah[(long)co * 4608 + k] = h;
  Al[(long)co * 4608 + k] = (f16)(v - (float)h);
}

__global__ __launch_bounds__(256) void prep_w2(const float* __restrict__ w,
                                               f16* __restrict__ Ah, f16* __restrict__ Al) {
  const int co = blockIdx.x;                      // < 512
  const int ci = blockIdx.y * 256 + threadIdx.x;  // < 1024
  float v = (co < 425) ? w[co * 1024 + ci] * 1024.f : 0.f;
  f16 h = (f16)v;
  Ah[co * 1024 + ci] = h;
  Al[co * 1024 + ci] = (f16)(v - (float)h);
}

__global__ __launch_bounds__(256) void prep_feat(const float* __restrict__ f,
                                                 f16* __restrict__ fph, f16* __restrict__ fpl) {
  __shared__ float lds[256][33];
  const int y = blockIdx.x, b = blockIdx.y, t = threadIdx.x;
  const int xx = t & 31, cig = t >> 5;
  const float* src = f + ((long)b * 512) * 1024 + y * 32;

  for (int half = 0; half < 2; ++half) {
    const int cibase = half * 256;
    for (int rep = 0; rep < 32; ++rep) {
      int ci = rep * 8 + cig;
      lds[ci][xx] = src[(long)(cibase + ci) * 1024 + xx];
    }
    __syncthreads();
    const long rowbase = ((long)(b * 34) + (y + 1)) * 34 + 1;
    for (int xp = 0; xp < 32; ++xp) {
      float v = lds[t][xp];
      f16 h = (f16)v;
      long o = (rowbase + xp) * 512 + cibase + t;
      fph[o] = h;
      fpl[o] = (f16)(v - (float)h);
    }
    __syncthreads();
  }
}

// ---------------------------------------------------------------------------
// gemm1: C[1024][32768] = A1(1024x4608) * im2col(features) + BN + leaky.
// 256x256 tile, 8 waves (2Mx4N), BK=32, 4 phases/K-tile, 2 barriers/K-tile,
// double-buffered LDS. Flat grid 512 with XCD swizzle.
// ---------------------------------------------------------------------------
__global__ __launch_bounds__(512, 2) void gemm1(
    const f16* __restrict__ A1h, const f16* __restrict__ A1l,
    const f16* __restrict__ Bh, const f16* __restrict__ Bl,
    const float* __restrict__ scale, const float* __restrict__ shift,
    f16* __restrict__ xth, f16* __restrict__ xtl) {
  __shared__ __align__(16) f16 S[65536];  // 128 KiB
  const int tid = threadIdx.x;
  const int l = tid & 63, w = tid >> 6;
  const int wm = w >> 2, wn = w & 3;
  const int rho = l & 15, cq = l >> 4;
  const int sc = (cq - rho) & 3;                       // stage source chunk
  const int roff = (rho + 16 * ((cq + rho) & 3)) * 8;  // swizzled read slot
  // XCD swizzle: bid%8 = XCD; XCD x gets mt = x>>1, nt = (x&1)*64 + bid/8.
  const int bid = blockIdx.x;
  const int xcd = bid & 7, j = bid >> 3;
  const int mt = xcd >> 1;
  const int nt = ((xcd & 1) << 6) + j;
  const int n0 = nt * 256, co0 = mt * 256;
  const int b = n0 >> 10, y0 = (n0 & 1023) >> 5;

  // stage units per wave
  const int a0u = (w & 3) + (w >> 2) * 8;  // A-half0 rows: units {0..3, 8..11}
  const int a1u = a0u + 4;                 // A-half1
  const int b0u = (w & 1) + (w >> 1) * 4;  // B-half0 cols
  const int b1u = b0u + 2;                 // B-half1

  const long aS0 = (long)(co0 + a0u * 16 + rho) * 4608 + sc * 8;
  const long aS1 = (long)(co0 + a1u * 16 + rho) * 4608 + sc * 8;
  const int c0 = b0u * 16 + rho, c1 = b1u * 16 + rho;
  const long bS0 = ((long)(b * 34 + y0 + (c0 >> 5)) * 34 + (c0 & 31)) * 512 + sc * 8;
  const long bS1 = ((long)(b * 34 + y0 + (c1 >> 5)) * 34 + (c1 & 31)) * 512 + sc * 8;

  f32x4 acc[8][4] = {};
  f16x8 ah[4], al[4], bh0[2], bl0[2], bh1[2], bl1[2];

  // prologue: stage tile 0 (order: a0u hi/lo, b0u hi/lo, a1u hi/lo, b1u hi/lo)
  gload16(A1h + aS0, &S[R_AH + a0u * 512]);
  gload16(A1l + aS0, &S[R_AL + a0u * 512]);
  gload16(Bh + bS0, &S[R_BH + b0u * 512]);
  gload16(Bl + bS0, &S[R_BL + b0u * 512]);
  gload16(A1h + aS1, &S[R_AH + a1u * 512]);
  gload16(A1l + aS1, &S[R_AL + a1u * 512]);
  gload16(Bh + bS1, &S[R_BH + b1u * 512]);
  gload16(Bl + bS1, &S[R_BL + b1u * 512]);
  ASM_VMCNT(4);  // first 4 (a0u,b0u) landed across all waves after barrier
  SBAR();

  for (int t = 0; t < 144; ++t) {
    const int cb = (t & 1) << 13;  // current buf (f16 elems)
    const int nb = 8192 - cb;      // next buf
    const int s1 = (t < 143) ? t + 1 : t;  // clamped prefetch tile
    const int ky1 = s1 / 48, r1 = s1 - ky1 * 48;
    const int kx1 = r1 >> 4, ci1 = (r1 & 15) << 5;
    const long kAn = (long)s1 * 32;
    const long kBn = (long)(ky1 * 34 + kx1) * 512 + ci1;

    // ---- P0: mq=0, nq=0 ----
#pragma unroll
    for (int mf = 0; mf < 4; ++mf) {
      const int u = wm * 8 + mf;
      ah[mf] = *(const f16x8*)&S[R_AH + cb + u * 512 + roff];
      al[mf] = *(const f16x8*)&S[R_AL + cb + u * 512 + roff];
    }
#pragma unroll
    for (int nf = 0; nf < 2; ++nf) {
      const int u = wn * 4 + nf;
      bh0[nf] = *(const f16x8*)&S[R_BH + cb + u * 512 + roff];
      bl0[nf] = *(const f16x8*)&S[R_BL + cb + u * 512 + roff];
    }
    gload16(A1h + aS0 + kAn, &S[R_AH + nb + a0u * 512]);
    gload16(A1l + aS0 + kAn, &S[R_AL + nb + a0u * 512]);
    ASM_VMCNT(2);  // drains P2(t-1)+P3(t-1) stages (a1u,b1u of cb)
    SBAR();
    __builtin_amdgcn_s_setprio(1);
#pragma unroll
    for (int mf = 0; mf < 4; ++mf)
#pragma unroll
      for (int nf = 0; nf < 2; ++nf) {
        acc[mf][nf] = MFMA(ah[mf], bh0[nf], acc[mf][nf]);
        acc[mf][nf] = MFMA(ah[mf], bl0[nf], acc[mf][nf]);
        acc[mf][nf] = MFMA(al[mf], bh0[nf], acc[mf][nf]);
      }
    __builtin_amdgcn_s_setprio(0);

    // ---- P1: mq=0, nq=1 ---- (reuse ah/al; read B-nq1; NO barrier)
#pragma unroll
    for (int nf = 0; nf < 2; ++nf) {
      const int u = wn * 4 + 2 + nf;
      bh1[nf] = *(const f16x8*)&S[R_BH + cb + u * 512 + roff];
      bl1[nf] = *(const f16x8*)&S[R_BL + cb + u * 512 + roff];
    }
    gload16(Bh + bS0 + kBn, &S[R_BH + nb + b0u * 512]);
    gload16(Bl + bS0 + kBn, &S[R_BL + nb + b0u * 512]);
    __builtin_amdgcn_s_setprio(1);
#pragma unroll
    for (int mf = 0; mf < 4; ++mf)
#pragma unroll
      for (int nf = 0; nf < 2; ++nf) {
        acc[mf][2 + nf] = MFMA(ah[mf], bh1[nf], acc[mf][2 + nf]);
        acc[mf][2 + nf] = MFMA(ah[mf], bl1[nf], acc[mf][2 + nf]);
        acc[mf][2 + nf] = MFMA(al[mf], bh1[nf], acc[mf][2 + nf]);
      }
    __builtin_amdgcn_s_setprio(0);

    // ---- P2: mq=1, nq=0 ---- (read A-mq1; reuse bh0/bl0; NO barrier)
#pragma unroll
    for (int mf = 0; mf < 4; ++mf) {
      const int u = wm * 8 + 4 + mf;
      ah[mf] = *(const f16x8*)&S[R_AH + cb + u * 512 + roff];
      al[mf] = *(const f16x8*)&S[R_AL + cb + u * 512 + roff];
    }
    gload16(A1h + aS1 + kAn, &S[R_AH + nb + a1u * 512]);
    gload16(A1l + aS1 + kAn, &S[R_AL + nb + a1u * 512]);
    __builtin_amdgcn_s_setprio(1);
#pragma unroll
    for (int mf = 0; mf < 4; ++mf)
#pragma unroll
      for (int nf = 0; nf < 2; ++nf) {
        acc[4 + mf][nf] = MFMA(ah[mf], bh0[nf], acc[4 + mf][nf]);
        acc[4 + mf][nf] = MFMA(ah[mf], bl0[nf], acc[4 + mf][nf]);
        acc[4 + mf][nf] = MFMA(al[mf], bh0[nf], acc[4 + mf][nf]);
      }
    __builtin_amdgcn_s_setprio(0);

    // ---- P3: mq=1, nq=1 ---- (no ds_reads: reuse ah/al + bh1/bl1)
    gload16(Bh + bS1 + kBn, &S[R_BH + nb + b1u * 512]);
    gload16(Bl + bS1 + kBn, &S[R_BL + nb + b1u * 512]);
    ASM_VMCNT(4);  // drains P0(t),P1(t) stages (next tile's a0u,b0u)
    SBAR();
    __builtin_amdgcn_s_setprio(1);
#pragma unroll
    for (int mf = 0; mf < 4; ++mf)
#pragma unroll
      for (int nf = 0; nf < 2; ++nf) {
        acc[4 + mf][2 + nf] = MFMA(ah[mf], bh1[nf], acc[4 + mf][2 + nf]);
        acc[4 + mf][2 + nf] = MFMA(ah[mf], bl1[nf], acc[4 + mf][2 + nf]);
        acc[4 + mf][2 + nf] = MFMA(al[mf], bh1[nf], acc[4 + mf][2 + nf]);
      }
    __builtin_amdgcn_s_setprio(0);
  }

  // epilogue: BN (1/1024 folded) + leaky, split to fp16 hi/lo, store NHWC
#pragma unroll
  for (int am = 0; am < 8; ++am) {
    const int cob = co0 + wm * 128 + am * 16 + cq * 4;
    const float4 scv = *(const float4*)(scale + cob);
    const float4 shv = *(const float4*)(shift + cob);
#pragma unroll
    for (int an = 0; an < 4; ++an) {
      const int col = n0 + wn * 64 + an * 16 + rho;
      f32x4 a = acc[am][an];
      float v0 = a[0] * scv.x + shv.x; v0 = v0 > 0.f ? v0 : 0.1f * v0;
      float v1 = a[1] * scv.y + shv.y; v1 = v1 > 0.f ? v1 : 0.1f * v1;
      float v2 = a[2] * scv.z + shv.z; v2 = v2 > 0.f ? v2 : 0.1f * v2;
      float v3 = a[3] * scv.w + shv.w; v3 = v3 > 0.f ? v3 : 0.1f * v3;
      f16 h0 = (f16)v0, h1 = (f16)v1, h2 = (f16)v2, h3 = (f16)v3;
      f16x4v hv = {h0, h1, h2, h3};
      f16x4v lv = {(f16)(v0 - (float)h0), (f16)(v1 - (float)h1),
                   (f16)(v2 - (float)h2), (f16)(v3 - (float)h3)};
      *(f16x4v*)(xth + (long)col * 1024 + cob) = hv;
      *(f16x4v*)(xtl + (long)col * 1024 + cob) = lv;
    }
  }
}

// ---------------------------------------------------------------------------
// gemm2: preds[n][512] = A2(512x1024) * xt (+bias, /1024). Same structure.
// grid (128 n-tiles, 2 m-tiles), block 512. K-tiles = 32.
// ---------------------------------------------------------------------------
__global__ __launch_bounds__(512, 2) void gemm2(
    const f16* __restrict__ A2h, const f16* __restrict__ A2l,
    const f16* __restrict__ Bh, const f16* __restrict__ Bl,
    const float* __restrict__ bias, float* __restrict__ preds) {
  __shared__ __align__(16) f16 S[65536];
  const int tid = threadIdx.x;
  const int l = tid & 63, w = tid >> 6;
  const int wm = w >> 2, wn = w & 3;
  const int rho = l & 15, cq = l >> 4;
  const int sc = (cq - rho) & 3;
  const int roff = (rho + 16 * ((cq + rho) & 3)) * 8;
  const int nt = blockIdx.x, mt = blockIdx.y;
  const int n0 = nt * 256, co0 = mt * 256;

  const int a0u = (w & 3) + (w >> 2) * 8;
  const int a1u = a0u + 4;
  const int b0u = (w & 1) + (w >> 1) * 4;
  const int b1u = b0u + 2;

  const long aS0 = (long)(co0 + a0u * 16 + rho) * 1024 + sc * 8;
  const long aS1 = (long)(co0 + a1u * 16 + rho) * 1024 + sc * 8;
  const long bS0 = (long)(n0 + b0u * 16 + rho) * 1024 + sc * 8;
  const long bS1 = (long)(n0 + b1u * 16 + rho) * 1024 + sc * 8;

  f32x4 acc[8][4] = {};
  f16x8 ah[4], al[4], bh0[2], bl0[2], bh1[2], bl1[2];

  gload16(A2h + aS0, &S[R_AH + a0u * 512]);
  gload16(A2l + aS0, &S[R_AL + a0u * 512]);
  gload16(Bh + bS0, &S[R_BH + b0u * 512]);
  gload16(Bl + bS0, &S[R_BL + b0u * 512]);
  gload16(A2h + aS1, &S[R_AH + a1u * 512]);
  gload16(A2l + aS1, &S[R_AL + a1u * 512]);
  gload16(Bh + bS1, &S[R_BH + b1u * 512]);
  gload16(Bl + bS1, &S[R_BL + b1u * 512]);
  ASM_VMCNT(4);
  SBAR();

  for (int t = 0; t < 32; ++t) {
    const int cb = (t & 1) << 13;
    const int nb = 8192 - cb;
    const long kn = (long)((t < 31) ? t + 1 : t) * 32;  // clamped prefetch

    // ---- P0 ----
#pragma unroll
    for (int mf = 0; mf < 4; ++mf) {
      const int u = wm * 8 + mf;
      ah[mf] = *(const f16x8*)&S[R_AH + cb + u * 512 + roff];
      al[mf] = *(const f16x8*)&S[R_AL + cb + u * 512 + roff];
    }
#pragma unroll
    for (int nf = 0; nf < 2; ++nf) {
      const int u = wn * 4 + nf;
      bh0[nf] = *(const f16x8*)&S[R_BH + cb + u * 512 + roff];
      bl0[nf] = *(const f16x8*)&S[R_BL + cb + u * 512 + roff];
    }
    gload16(A2h + aS0 + kn, &S[R_AH + nb + a0u * 512]);
    gload16(A2l + aS0 + kn, &S[R_AL + nb + a0u * 512]);
    ASM_VMCNT(2);
    SBAR();
    __builtin_amdgcn_s_setprio(1);
#pragma unroll
    for (int mf = 0; mf < 4; ++mf)
#pragma unroll
      for (int nf = 0; nf < 2; ++nf) {
        acc[mf][nf] = MFMA(ah[mf], bh0[nf], acc[mf][nf]);
        acc[mf][nf] = MFMA(ah[mf], bl0[nf], acc[mf][nf]);
        acc[mf][nf] = MFMA(al[mf], bh0[nf], acc[mf][nf]);
      }
    __builtin_amdgcn_s_setprio(0);

    // ---- P1 ---- (NO barrier)
#pragma unroll
    for (int nf = 0; nf < 2; ++nf) {
      const int u = wn * 4 + 2 + nf;
      bh1[nf] = *(const f16x8*)&S[R_BH + cb + u * 512 + roff];
      bl1[nf] = *(const f16x8*)&S[R_BL + cb + u * 512 + roff];
    }
    gload16(Bh + bS0 + kn, &S[R_BH + nb + b0u * 512]);
    gload16(Bl + bS0 + kn, &S[R_BL + nb + b0u * 512]);
    __builtin_amdgcn_s_setprio(1);
#pragma unroll
    for (int mf = 0; mf < 4; ++mf)
#pragma unroll
      for (int nf = 0; nf < 2; ++nf) {
        acc[mf][2 + nf] = MFMA(ah[mf], bh1[nf], acc[mf][2 + nf]);
        acc[mf][2 + nf] = MFMA(ah[mf], bl1[nf], acc[mf][2 + nf]);
        acc[mf][2 + nf] = MFMA(al[mf], bh1[nf], acc[mf][2 + nf]);
      }
    __builtin_amdgcn_s_setprio(0);

    // ---- P2 ---- (NO barrier)
#pragma unroll
    for (int mf = 0; mf < 4; ++mf) {
      const int u = wm * 8 + 4 + mf;
      ah[mf] = *(const f16x8*)&S[R_AH + cb + u * 512 + roff];
      al[mf] = *(const f16x8*)&S[R_AL + cb + u * 512 + roff];
    }
    gload16(A2h + aS1 + kn, &S[R_AH + nb + a1u * 512]);
    gload16(A2l + aS1 + kn, &S[R_AL + nb + a1u * 512]);
    __builtin_amdgcn_s_setprio(1);
#pragma unroll
    for (int mf = 0; mf < 4; ++mf)
#pragma unroll
      for (int nf = 0; nf < 2; ++nf) {
        acc[4 + mf][nf] = MFMA(ah[mf], bh0[nf], acc[4 + mf][nf]);
        acc[4 + mf][nf] = MFMA(ah[mf], bl0[nf], acc[4 + mf][nf]);
        acc[4 + mf][nf] = MFMA(al[mf], bh0[nf], acc[4 + mf][nf]);
      }
    __builtin_amdgcn_s_setprio(0);

    // ---- P3 ----
    gload16(Bh + bS1 + kn, &S[R_BH + nb + b1u * 512]);
    gload16(Bl + bS1 + kn, &S[R_BL + nb + b1u * 512]);
    ASM_VMCNT(4);
    SBAR();
    __builtin_amdgcn_s_setprio(1);
#pragma unroll
    for (int mf = 0; mf < 4; ++mf)
#pragma unroll
      for (int nf = 0; nf < 2; ++nf) {
        acc[4 + mf][2 + nf] = MFMA(ah[mf], bh1[nf], acc[4 + mf][2 + nf]);
        acc[4 + mf][2 + nf] = MFMA(ah[mf], bl1[nf], acc[4 + mf][2 + nf]);
        acc[4 + mf][2 + nf] = MFMA(al[mf], bh1[nf], acc[4 + mf][2 + nf]);
      }
    __builtin_amdgcn_s_setprio(0);
  }

#pragma unroll
  for (int am = 0; am < 8; ++am) {
    const int cob = co0 + wm * 128 + am * 16 + cq * 4;
    const float4 bi = *(const float4*)(bias + cob);
#pragma unroll
    for (int an = 0; an < 4; ++an) {
      const int col = n0 + wn * 64 + an * 16 + rho;
      f32x4 a = acc[am][an];
      float4 o;
      o.x = a[0] * 9.765625e-4f + bi.x;
      o.y = a[1] * 9.765625e-4f + bi.y;
      o.z = a[2] * 9.765625e-4f + bi.z;
      o.w = a[3] * 9.765625e-4f + bi.w;
      *(float4*)(preds + (long)col * 512 + cob) = o;
    }
  }
}

// ---------------------------------------------------------------------------
__global__ __launch_bounds__(256) void decode(const float* __restrict__ preds,
                                              float* __restrict__ out) {
  const int t = blockIdx.x * 256 + threadIdx.x;  // < 163840
  const int b = t / 5120, rem = t % 5120, pos = rem / 5, a = rem % 5;
  const int n = (b << 10) + pos;
  const float* p = preds + (long)n * 512 + a * 85;

  float tx = p[0], ty = p[1], tw = p[2], th = p[3], to = p[4];
  float mx = p[5];
  int arg = 0;
  for (int i = 1; i < 80; ++i) {
    float v = p[5 + i];
    if (v > mx) { mx = v; arg = i; }
  }
  float sum = 0.f;
  for (int i = 0; i < 80; ++i) sum += expf(p[5 + i] - mx);

  float obj = 1.f / (1.f + expf(-to));
  float score = obj / sum;
  float bx = 1.f / (1.f + expf(-tx));
  float by = 1.f / (1.f + expf(-ty));
  float bw = expf(fminf(tw, 8.f));
  float bh2 = expf(fminf(th, 8.f));
  float cx = (bx + (float)(pos & 31)) * 32.f;
  float cy = (by + (float)(pos >> 5)) * 32.f;
  float pw = c_AW[a] * bw;
  float ph = c_AH_[a] * bh2;
  float x1 = fminf(fmaxf(cx - 0.5f * pw, 0.f), 1023.f);
  float y1 = fminf(fmaxf(cy - 0.5f * ph, 0.f), 1023.f);
  float x2 = fminf(fmaxf(cx + 0.5f * pw, 0.f), 1023.f);
  float y2 = fminf(fmaxf(cy + 0.5f * ph, 0.f), 1023.f);

  const long o = ((long)b * 5120 + pos * 5 + a) * 5;
  out[o + 0] = x1;
  out[o + 1] = y1;
  out[o + 2] = x2;
  out[o + 3] = y2;
  out[o + 4] = score;
  out[819200 + (long)b * 5120 + pos * 5 + a] = (float)arg;
}

// ---------------------------------------------------------------------------
// workspace layout (bytes):
//   0          fph  [32][34][34][512] f16   37,879,808
//   37879808   fpl                          37,879,808
//   75759616   A1h  [1024][4608] f16         9,437,184
//   85196800   A1l                           9,437,184
//   94633984   A2h  [512][1024] f16          1,048,576
//   95682560   A2l                           1,048,576
//   96731136   scale f32[1024]                   4,096
//   96735232   shift f32[1024]                   4,096
//   96739328   bias  f32[512]                    2,048
//   96741376   xth  [32768][1024] f16       67,108,864
//   163850240  xtl                          67,108,864
//   total 230,959,104;  preds f32[32768][512] aliases offset 0
// ---------------------------------------------------------------------------
extern "C" void kernel_launch(void* const* d_in, const int* in_sizes, int n_in,
                              void* d_out, int out_size, void* d_ws, size_t ws_size,
                              hipStream_t stream) {
  (void)in_sizes; (void)n_in; (void)out_size; (void)ws_size;
  const float* features = (const float*)d_in[0];
  const float* conv1_w = (const float*)d_in[1];
  const float* bn_g = (const float*)d_in[2];
  const float* bn_b = (const float*)d_in[3];
  const float* bn_m = (const float*)d_in[4];
  const float* bn_v = (const float*)d_in[5];
  const float* conv2_w = (const float*)d_in[6];
  const float* conv2_b = (const float*)d_in[7];
  float* out = (float*)d_out;
  char* ws = (char*)d_ws;

  f16* fph = (f16*)(ws + 0);
  f16* fpl = (f16*)(ws + 37879808L);
  f16* A1h = (f16*)(ws + 75759616L);
  f16* A1l = (f16*)(ws + 85196800L);
  f16* A2h = (f16*)(ws + 94633984L);
  f16* A2l = (f16*)(ws + 95682560L);
  float* scale = (float*)(ws + 96731136L);
  float* shift = (float*)(ws + 96735232L);
  float* bias = (float*)(ws + 96739328L);
  f16* xth = (f16*)(ws + 96741376L);
  f16* xtl = (f16*)(ws + 163850240L);
  float* preds = (float*)(ws + 0);  // alias: fp dead after gemm1

  hipMemsetAsync(ws, 0, 75759616L, stream);  // zero padded feature rings
  prep_misc<<<1, 1024, 0, stream>>>(bn_g, bn_b, bn_m, bn_v, conv2_b, scale, shift, bias);
  prep_w1<<<dim3(1024, 18), 256, 0, stream>>>(conv1_w, A1h, A1l);
  prep_w2<<<dim3(512, 4), 256, 0, stream>>>(conv2_w, A2h, A2l);
  prep_feat<<<dim3(32, 32), 256, 0, stream>>>(features, fph, fpl);
  gemm1<<<512, 512, 0, stream>>>(A1h, A1l, fph, fpl, scale, shift, xth, xtl);
  gemm2<<<dim3(128, 2), 512, 0, stream>>>(A2h, A2l, xth, xtl, bias, preds);
  decode<<<640, 256, 0, stream>>>(preds, out);
}

// Round 11
// 876.558 us; speedup vs baseline: 1.0187x; 1.0187x over previous
//
#include <hip/hip_runtime.h>

// ---------------------------------------------------------------------------
// YOLOv2 head on MI355X (gfx950).
// conv1 3x3 (512->1024) + BN + leaky -> conv2 1x1 (1024->425) + bias -> decode
// fp16 3-term split GEMM (ah*bh + ah*bl + al*bh) for fp32-class accuracy.
// R11 = R9 (best: 723us gemm1, 66% MfmaUtil, 2 barriers/K-tile) + tail work:
//   - swizzle reverted (R10: FETCH x2, time neutral -> memory off crit path)
//   - prep_feat: single-pass transpose, f16x2 vectorized stores
//   - 75.8 MB memset replaced by 8.7 MB ring-zero kernel
// ---------------------------------------------------------------------------

typedef _Float16 f16;
typedef _Float16 f16x2 __attribute__((ext_vector_type(2)));
typedef _Float16 f16x8 __attribute__((ext_vector_type(8)));
typedef _Float16 f16x4v __attribute__((ext_vector_type(4)));
typedef float    f32x4 __attribute__((ext_vector_type(4)));

__device__ __forceinline__ void gload16(const f16* g, f16* l) {
  __builtin_amdgcn_global_load_lds(
      (const __attribute__((address_space(1))) void*)g,
      (__attribute__((address_space(3))) void*)l, 16, 0, 0);
}

#define MFMA(a, b, c) __builtin_amdgcn_mfma_f32_16x16x32_f16(a, b, c, 0, 0, 0)
#define ASM_VMCNT(N) asm volatile("s_waitcnt vmcnt(" #N ")" ::: "memory")
#define SBAR()                           \
  {                                      \
    __builtin_amdgcn_s_barrier();        \
    __builtin_amdgcn_sched_barrier(0);   \
  }

// LDS region bases (f16 elements): each region 2 bufs x 16 units x 512
#define R_AH 0
#define R_AL 16384
#define R_BH 32768
#define R_BL 49152

// anchors
__device__ const float c_AW[5] = {42.f, 98.f, 180.f, 300.f, 400.f};
__device__ const float c_AH_[5] = {45.f, 130.f, 260.f, 180.f, 400.f};

// ---------------------------------------------------------------------------
__global__ void prep_misc(const float* __restrict__ g, const float* __restrict__ be,
                          const float* __restrict__ mn, const float* __restrict__ vr,
                          const float* __restrict__ b2,
                          float* __restrict__ scale, float* __restrict__ shift,
                          float* __restrict__ bias) {
  int i = threadIdx.x;  // 1024 threads
  float s = g[i] / sqrtf(vr[i] + 1e-5f);
  shift[i] = be[i] - mn[i] * s;
  scale[i] = s * (1.0f / 1024.0f);
  if (i < 512) bias[i] = (i < 425) ? b2[i] : 0.f;
}

__global__ __launch_bounds__(256) void prep_w1(const float* __restrict__ w,
                                               f16* __restrict__ Ah, f16* __restrict__ Al) {
  const int co = blockIdx.x;
  const int k = blockIdx.y * 256 + threadIdx.x;  // < 4608
  const int ky = k / 1536, rem = k - ky * 1536;
  const int kx = rem >> 9, ci = rem & 511;
  float v = w[((co * 512 + ci) * 3 + ky) * 3 + kx] * 1024.f;
  f16 h = (f16)v;
  Ah[(long)co * 4608 + k] = h;
  Al[(long)co * 4608 + k] = (f16)(v - (float)h);
}

__global__ __launch_bounds__(256) void prep_w2(const float* __restrict__ w,
                                               f16* __restrict__ Ah, f16* __restrict__ Al) {
  const int co = blockIdx.x;                      // < 512
  const int ci = blockIdx.y * 256 + threadIdx.x;  // < 1024
  float v = (co < 425) ? w[co * 1024 + ci] * 1024.f : 0.f;
  f16 h = (f16)v;
  Ah[co * 1024 + ci] = h;
  Al[co * 1024 + ci] = (f16)(v - (float)h);
}

// ---------------------------------------------------------------------------
// ring_zero: zero the 1-pixel pad ring of fp[b][34][34][512] (hi+lo).
// 132 ring cells per image; each cell = 512 f16 = 1KB. grid (132, 32), blk 64.
// ---------------------------------------------------------------------------
__global__ __launch_bounds__(64) void ring_zero(f16* __restrict__ fph,
                                                f16* __restrict__ fpl) {
  const int cell = blockIdx.x, b = blockIdx.y;
  int r, c;
  if (cell < 34)       { r = 0;          c = cell; }
  else if (cell < 68)  { r = 33;         c = cell - 34; }
  else if (cell < 100) { r = cell - 67;  c = 0; }   // 1..32
  else                 { r = cell - 99;  c = 33; }  // 1..32
  const long o = (((long)b * 34 + r) * 34 + c) * 512 + threadIdx.x * 8;
  f16x8 z = {};
  *(f16x8*)(fph + o) = z;
  *(f16x8*)(fpl + o) = z;
}

// ---------------------------------------------------------------------------
// prep_feat: features NCHW fp32 -> padded NHWC fp16 hi/lo fp[b][34][34][512].
// Single pass: LDS transpose of 512ch x 32x, f16x2 vectorized stores.
// grid (32 y, 32 b), block 256.
// ---------------------------------------------------------------------------
__global__ __launch_bounds__(256) void prep_feat(const float* __restrict__ f,
                                                 f16* __restrict__ fph, f16* __restrict__ fpl) {
  __shared__ float lds[512][33];
  const int y = blockIdx.x, b = blockIdx.y, t = threadIdx.x;
  const int xx = t & 31, cig = t >> 5;  // 8 ci rows per rep
  const float* src = f + ((long)b * 512) * 1024 + y * 32;

#pragma unroll 4
  for (int rep = 0; rep < 64; ++rep) {
    int ci = rep * 8 + cig;
    lds[ci][xx] = src[(long)ci * 1024 + xx];
  }
  __syncthreads();

  // thread t owns channel pair (2t, 2t+1); write 32 columns as f16x2
  const long rowbase = ((long)(b * 34) + (y + 1)) * 34 + 1;
  const int c0 = 2 * t;
#pragma unroll 4
  for (int xp = 0; xp < 32; ++xp) {
    float v0 = lds[c0][xp], v1 = lds[c0 + 1][xp];
    f16 h0 = (f16)v0, h1 = (f16)v1;
    f16x2 hv = {h0, h1};
    f16x2 lv = {(f16)(v0 - (float)h0), (f16)(v1 - (float)h1)};
    const long o = (rowbase + xp) * 512 + c0;
    *(f16x2*)(fph + o) = hv;
    *(f16x2*)(fpl + o) = lv;
  }
}

// ---------------------------------------------------------------------------
// gemm1: C[1024][32768] = A1(1024x4608) * im2col(features) + BN + leaky.
// 256x256 tile, 8 waves (2Mx4N), BK=32, 4 phases/K-tile, 2 barriers/K-tile,
// double-buffered LDS. grid (128 n-tiles, 4 m-tiles), block 512.
// ---------------------------------------------------------------------------
__global__ __launch_bounds__(512, 2) void gemm1(
    const f16* __restrict__ A1h, const f16* __restrict__ A1l,
    const f16* __restrict__ Bh, const f16* __restrict__ Bl,
    const float* __restrict__ scale, const float* __restrict__ shift,
    f16* __restrict__ xth, f16* __restrict__ xtl) {
  __shared__ __align__(16) f16 S[65536];  // 128 KiB
  const int tid = threadIdx.x;
  const int l = tid & 63, w = tid >> 6;
  const int wm = w >> 2, wn = w & 3;
  const int rho = l & 15, cq = l >> 4;
  const int sc = (cq - rho) & 3;                       // stage source chunk
  const int roff = (rho + 16 * ((cq + rho) & 3)) * 8;  // swizzled read slot
  const int nt = blockIdx.x, mt = blockIdx.y;
  const int n0 = nt * 256, co0 = mt * 256;
  const int b = n0 >> 10, y0 = (n0 & 1023) >> 5;

  // stage units per wave
  const int a0u = (w & 3) + (w >> 2) * 8;  // A-half0 rows: units {0..3, 8..11}
  const int a1u = a0u + 4;                 // A-half1
  const int b0u = (w & 1) + (w >> 1) * 4;  // B-half0 cols
  const int b1u = b0u + 2;                 // B-half1

  const long aS0 = (long)(co0 + a0u * 16 + rho) * 4608 + sc * 8;
  const long aS1 = (long)(co0 + a1u * 16 + rho) * 4608 + sc * 8;
  const int c0 = b0u * 16 + rho, c1 = b1u * 16 + rho;
  const long bS0 = ((long)(b * 34 + y0 + (c0 >> 5)) * 34 + (c0 & 31)) * 512 + sc * 8;
  const long bS1 = ((long)(b * 34 + y0 + (c1 >> 5)) * 34 + (c1 & 31)) * 512 + sc * 8;

  f32x4 acc[8][4] = {};
  f16x8 ah[4], al[4], bh0[2], bl0[2], bh1[2], bl1[2];

  // prologue: stage tile 0 (order: a0u hi/lo, b0u hi/lo, a1u hi/lo, b1u hi/lo)
  gload16(A1h + aS0, &S[R_AH + a0u * 512]);
  gload16(A1l + aS0, &S[R_AL + a0u * 512]);
  gload16(Bh + bS0, &S[R_BH + b0u * 512]);
  gload16(Bl + bS0, &S[R_BL + b0u * 512]);
  gload16(A1h + aS1, &S[R_AH + a1u * 512]);
  gload16(A1l + aS1, &S[R_AL + a1u * 512]);
  gload16(Bh + bS1, &S[R_BH + b1u * 512]);
  gload16(Bl + bS1, &S[R_BL + b1u * 512]);
  ASM_VMCNT(4);  // first 4 (a0u,b0u) landed across all waves after barrier
  SBAR();

  for (int t = 0; t < 144; ++t) {
    const int cb = (t & 1) << 13;  // current buf (f16 elems)
    const int nb = 8192 - cb;      // next buf
    const int s1 = (t < 143) ? t + 1 : t;  // clamped prefetch tile
    const int ky1 = s1 / 48, r1 = s1 - ky1 * 48;
    const int kx1 = r1 >> 4, ci1 = (r1 & 15) << 5;
    const long kAn = (long)s1 * 32;
    const long kBn = (long)(ky1 * 34 + kx1) * 512 + ci1;

    // ---- P0: mq=0, nq=0 ----
#pragma unroll
    for (int mf = 0; mf < 4; ++mf) {
      const int u = wm * 8 + mf;
      ah[mf] = *(const f16x8*)&S[R_AH + cb + u * 512 + roff];
      al[mf] = *(const f16x8*)&S[R_AL + cb + u * 512 + roff];
    }
#pragma unroll
    for (int nf = 0; nf < 2; ++nf) {
      const int u = wn * 4 + nf;
      bh0[nf] = *(const f16x8*)&S[R_BH + cb + u * 512 + roff];
      bl0[nf] = *(const f16x8*)&S[R_BL + cb + u * 512 + roff];
    }
    gload16(A1h + aS0 + kAn, &S[R_AH + nb + a0u * 512]);
    gload16(A1l + aS0 + kAn, &S[R_AL + nb + a0u * 512]);
    ASM_VMCNT(2);  // drains P2(t-1)+P3(t-1) stages (a1u,b1u of cb)
    SBAR();
    __builtin_amdgcn_s_setprio(1);
#pragma unroll
    for (int mf = 0; mf < 4; ++mf)
#pragma unroll
      for (int nf = 0; nf < 2; ++nf) {
        acc[mf][nf] = MFMA(ah[mf], bh0[nf], acc[mf][nf]);
        acc[mf][nf] = MFMA(ah[mf], bl0[nf], acc[mf][nf]);
        acc[mf][nf] = MFMA(al[mf], bh0[nf], acc[mf][nf]);
      }
    __builtin_amdgcn_s_setprio(0);

    // ---- P1: mq=0, nq=1 ---- (reuse ah/al; read B-nq1; NO barrier)
#pragma unroll
    for (int nf = 0; nf < 2; ++nf) {
      const int u = wn * 4 + 2 + nf;
      bh1[nf] = *(const f16x8*)&S[R_BH + cb + u * 512 + roff];
      bl1[nf] = *(const f16x8*)&S[R_BL + cb + u * 512 + roff];
    }
    gload16(Bh + bS0 + kBn, &S[R_BH + nb + b0u * 512]);
    gload16(Bl + bS0 + kBn, &S[R_BL + nb + b0u * 512]);
    __builtin_amdgcn_s_setprio(1);
#pragma unroll
    for (int mf = 0; mf < 4; ++mf)
#pragma unroll
      for (int nf = 0; nf < 2; ++nf) {
        acc[mf][2 + nf] = MFMA(ah[mf], bh1[nf], acc[mf][2 + nf]);
        acc[mf][2 + nf] = MFMA(ah[mf], bl1[nf], acc[mf][2 + nf]);
        acc[mf][2 + nf] = MFMA(al[mf], bh1[nf], acc[mf][2 + nf]);
      }
    __builtin_amdgcn_s_setprio(0);

    // ---- P2: mq=1, nq=0 ---- (read A-mq1; reuse bh0/bl0; NO barrier)
#pragma unroll
    for (int mf = 0; mf < 4; ++mf) {
      const int u = wm * 8 + 4 + mf;
      ah[mf] = *(const f16x8*)&S[R_AH + cb + u * 512 + roff];
      al[mf] = *(const f16x8*)&S[R_AL + cb + u * 512 + roff];
    }
    gload16(A1h + aS1 + kAn, &S[R_AH + nb + a1u * 512]);
    gload16(A1l + aS1 + kAn, &S[R_AL + nb + a1u * 512]);
    __builtin_amdgcn_s_setprio(1);
#pragma unroll
    for (int mf = 0; mf < 4; ++mf)
#pragma unroll
      for (int nf = 0; nf < 2; ++nf) {
        acc[4 + mf][nf] = MFMA(ah[mf], bh0[nf], acc[4 + mf][nf]);
        acc[4 + mf][nf] = MFMA(ah[mf], bl0[nf], acc[4 + mf][nf]);
        acc[4 + mf][nf] = MFMA(al[mf], bh0[nf], acc[4 + mf][nf]);
      }
    __builtin_amdgcn_s_setprio(0);

    // ---- P3: mq=1, nq=1 ---- (no ds_reads: reuse ah/al + bh1/bl1)
    gload16(Bh + bS1 + kBn, &S[R_BH + nb + b1u * 512]);
    gload16(Bl + bS1 + kBn, &S[R_BL + nb + b1u * 512]);
    ASM_VMCNT(4);  // drains P0(t),P1(t) stages (next tile's a0u,b0u)
    SBAR();
    __builtin_amdgcn_s_setprio(1);
#pragma unroll
    for (int mf = 0; mf < 4; ++mf)
#pragma unroll
      for (int nf = 0; nf < 2; ++nf) {
        acc[4 + mf][2 + nf] = MFMA(ah[mf], bh1[nf], acc[4 + mf][2 + nf]);
        acc[4 + mf][2 + nf] = MFMA(ah[mf], bl1[nf], acc[4 + mf][2 + nf]);
        acc[4 + mf][2 + nf] = MFMA(al[mf], bh1[nf], acc[4 + mf][2 + nf]);
      }
    __builtin_amdgcn_s_setprio(0);
  }

  // epilogue: BN (1/1024 folded) + leaky, split to fp16 hi/lo, store NHWC
#pragma unroll
  for (int am = 0; am < 8; ++am) {
    const int cob = co0 + wm * 128 + am * 16 + cq * 4;
    const float4 scv = *(const float4*)(scale + cob);
    const float4 shv = *(const float4*)(shift + cob);
#pragma unroll
    for (int an = 0; an < 4; ++an) {
      const int col = n0 + wn * 64 + an * 16 + rho;
      f32x4 a = acc[am][an];
      float v0 = a[0] * scv.x + shv.x; v0 = v0 > 0.f ? v0 : 0.1f * v0;
      float v1 = a[1] * scv.y + shv.y; v1 = v1 > 0.f ? v1 : 0.1f * v1;
      float v2 = a[2] * scv.z + shv.z; v2 = v2 > 0.f ? v2 : 0.1f * v2;
      float v3 = a[3] * scv.w + shv.w; v3 = v3 > 0.f ? v3 : 0.1f * v3;
      f16 h0 = (f16)v0, h1 = (f16)v1, h2 = (f16)v2, h3 = (f16)v3;
      f16x4v hv = {h0, h1, h2, h3};
      f16x4v lv = {(f16)(v0 - (float)h0), (f16)(v1 - (float)h1),
                   (f16)(v2 - (float)h2), (f16)(v3 - (float)h3)};
      *(f16x4v*)(xth + (long)col * 1024 + cob) = hv;
      *(f16x4v*)(xtl + (long)col * 1024 + cob) = lv;
    }
  }
}

// ---------------------------------------------------------------------------
// gemm2: preds[n][512] = A2(512x1024) * xt (+bias, /1024). Same structure.
// grid (128 n-tiles, 2 m-tiles), block 512. K-tiles = 32.
// ---------------------------------------------------------------------------
__global__ __launch_bounds__(512, 2) void gemm2(
    const f16* __restrict__ A2h, const f16* __restrict__ A2l,
    const f16* __restrict__ Bh, const f16* __restrict__ Bl,
    const float* __restrict__ bias, float* __restrict__ preds) {
  __shared__ __align__(16) f16 S[65536];
  const int tid = threadIdx.x;
  const int l = tid & 63, w = tid >> 6;
  const int wm = w >> 2, wn = w & 3;
  const int rho = l & 15, cq = l >> 4;
  const int sc = (cq - rho) & 3;
  const int roff = (rho + 16 * ((cq + rho) & 3)) * 8;
  const int nt = blockIdx.x, mt = blockIdx.y;
  const int n0 = nt * 256, co0 = mt * 256;

  const int a0u = (w & 3) + (w >> 2) * 8;
  const int a1u = a0u + 4;
  const int b0u = (w & 1) + (w >> 1) * 4;
  const int b1u = b0u + 2;

  const long aS0 = (long)(co0 + a0u * 16 + rho) * 1024 + sc * 8;
  const long aS1 = (long)(co0 + a1u * 16 + rho) * 1024 + sc * 8;
  const long bS0 = (long)(n0 + b0u * 16 + rho) * 1024 + sc * 8;
  const long bS1 = (long)(n0 + b1u * 16 + rho) * 1024 + sc * 8;

  f32x4 acc[8][4] = {};
  f16x8 ah[4], al[4], bh0[2], bl0[2], bh1[2], bl1[2];

  gload16(A2h + aS0, &S[R_AH + a0u * 512]);
  gload16(A2l + aS0, &S[R_AL + a0u * 512]);
  gload16(Bh + bS0, &S[R_BH + b0u * 512]);
  gload16(Bl + bS0, &S[R_BL + b0u * 512]);
  gload16(A2h + aS1, &S[R_AH + a1u * 512]);
  gload16(A2l + aS1, &S[R_AL + a1u * 512]);
  gload16(Bh + bS1, &S[R_BH + b1u * 512]);
  gload16(Bl + bS1, &S[R_BL + b1u * 512]);
  ASM_VMCNT(4);
  SBAR();

  for (int t = 0; t < 32; ++t) {
    const int cb = (t & 1) << 13;
    const int nb = 8192 - cb;
    const long kn = (long)((t < 31) ? t + 1 : t) * 32;  // clamped prefetch

    // ---- P0 ----
#pragma unroll
    for (int mf = 0; mf < 4; ++mf) {
      const int u = wm * 8 + mf;
      ah[mf] = *(const f16x8*)&S[R_AH + cb + u * 512 + roff];
      al[mf] = *(const f16x8*)&S[R_AL + cb + u * 512 + roff];
    }
#pragma unroll
    for (int nf = 0; nf < 2; ++nf) {
      const int u = wn * 4 + nf;
      bh0[nf] = *(const f16x8*)&S[R_BH + cb + u * 512 + roff];
      bl0[nf] = *(const f16x8*)&S[R_BL + cb + u * 512 + roff];
    }
    gload16(A2h + aS0 + kn, &S[R_AH + nb + a0u * 512]);
    gload16(A2l + aS0 + kn, &S[R_AL + nb + a0u * 512]);
    ASM_VMCNT(2);
    SBAR();
    __builtin_amdgcn_s_setprio(1);
#pragma unroll
    for (int mf = 0; mf < 4; ++mf)
#pragma unroll
      for (int nf = 0; nf < 2; ++nf) {
        acc[mf][nf] = MFMA(ah[mf], bh0[nf], acc[mf][nf]);
        acc[mf][nf] = MFMA(ah[mf], bl0[nf], acc[mf][nf]);
        acc[mf][nf] = MFMA(al[mf], bh0[nf], acc[mf][nf]);
      }
    __builtin_amdgcn_s_setprio(0);

    // ---- P1 ---- (NO barrier)
#pragma unroll
    for (int nf = 0; nf < 2; ++nf) {
      const int u = wn * 4 + 2 + nf;
      bh1[nf] = *(const f16x8*)&S[R_BH + cb + u * 512 + roff];
      bl1[nf] = *(const f16x8*)&S[R_BL + cb + u * 512 + roff];
    }
    gload16(Bh + bS0 + kn, &S[R_BH + nb + b0u * 512]);
    gload16(Bl + bS0 + kn, &S[R_BL + nb + b0u * 512]);
    __builtin_amdgcn_s_setprio(1);
#pragma unroll
    for (int mf = 0; mf < 4; ++mf)
#pragma unroll
      for (int nf = 0; nf < 2; ++nf) {
        acc[mf][2 + nf] = MFMA(ah[mf], bh1[nf], acc[mf][2 + nf]);
        acc[mf][2 + nf] = MFMA(ah[mf], bl1[nf], acc[mf][2 + nf]);
        acc[mf][2 + nf] = MFMA(al[mf], bh1[nf], acc[mf][2 + nf]);
      }
    __builtin_amdgcn_s_setprio(0);

    // ---- P2 ---- (NO barrier)
#pragma unroll
    for (int mf = 0; mf < 4; ++mf) {
      const int u = wm * 8 + 4 + mf;
      ah[mf] = *(const f16x8*)&S[R_AH + cb + u * 512 + roff];
      al[mf] = *(const f16x8*)&S[R_AL + cb + u * 512 + roff];
    }
    gload16(A2h + aS1 + kn, &S[R_AH + nb + a1u * 512]);
    gload16(A2l + aS1 + kn, &S[R_AL + nb + a1u * 512]);
    __builtin_amdgcn_s_setprio(1);
#pragma unroll
    for (int mf = 0; mf < 4; ++mf)
#pragma unroll
      for (int nf = 0; nf < 2; ++nf) {
        acc[4 + mf][nf] = MFMA(ah[mf], bh0[nf], acc[4 + mf][nf]);
        acc[4 + mf][nf] = MFMA(ah[mf], bl0[nf], acc[4 + mf][nf]);
        acc[4 + mf][nf] = MFMA(al[mf], bh0[nf], acc[4 + mf][nf]);
      }
    __builtin_amdgcn_s_setprio(0);

    // ---- P3 ----
    gload16(Bh + bS1 + kn, &S[R_BH + nb + b1u * 512]);
    gload16(Bl + bS1 + kn, &S[R_BL + nb + b1u * 512]);
    ASM_VMCNT(4);
    SBAR();
    __builtin_amdgcn_s_setprio(1);
#pragma unroll
    for (int mf = 0; mf < 4; ++mf)
#pragma unroll
      for (int nf = 0; nf < 2; ++nf) {
        acc[4 + mf][2 + nf] = MFMA(ah[mf], bh1[nf], acc[4 + mf][2 + nf]);
        acc[4 + mf][2 + nf] = MFMA(ah[mf], bl1[nf], acc[4 + mf][2 + nf]);
        acc[4 + mf][2 + nf] = MFMA(al[mf], bh1[nf], acc[4 + mf][2 + nf]);
      }
    __builtin_amdgcn_s_setprio(0);
  }

#pragma unroll
  for (int am = 0; am < 8; ++am) {
    const int cob = co0 + wm * 128 + am * 16 + cq * 4;
    const float4 bi = *(const float4*)(bias + cob);
#pragma unroll
    for (int an = 0; an < 4; ++an) {
      const int col = n0 + wn * 64 + an * 16 + rho;
      f32x4 a = acc[am][an];
      float4 o;
      o.x = a[0] * 9.765625e-4f + bi.x;
      o.y = a[1] * 9.765625e-4f + bi.y;
      o.z = a[2] * 9.765625e-4f + bi.z;
      o.w = a[3] * 9.765625e-4f + bi.w;
      *(float4*)(preds + (long)col * 512 + cob) = o;
    }
  }
}

// ---------------------------------------------------------------------------
__global__ __launch_bounds__(256) void decode(const float* __restrict__ preds,
                                              float* __restrict__ out) {
  const int t = blockIdx.x * 256 + threadIdx.x;  // < 163840
  const int b = t / 5120, rem = t % 5120, pos = rem / 5, a = rem % 5;
  const int n = (b << 10) + pos;
  const float* p = preds + (long)n * 512 + a * 85;

  float tx = p[0], ty = p[1], tw = p[2], th = p[3], to = p[4];
  float mx = p[5];
  int arg = 0;
  for (int i = 1; i < 80; ++i) {
    float v = p[5 + i];
    if (v > mx) { mx = v; arg = i; }
  }
  float sum = 0.f;
  for (int i = 0; i < 80; ++i) sum += expf(p[5 + i] - mx);

  float obj = 1.f / (1.f + expf(-to));
  float score = obj / sum;
  float bx = 1.f / (1.f + expf(-tx));
  float by = 1.f / (1.f + expf(-ty));
  float bw = expf(fminf(tw, 8.f));
  float bh2 = expf(fminf(th, 8.f));
  float cx = (bx + (float)(pos & 31)) * 32.f;
  float cy = (by + (float)(pos >> 5)) * 32.f;
  float pw = c_AW[a] * bw;
  float ph = c_AH_[a] * bh2;
  float x1 = fminf(fmaxf(cx - 0.5f * pw, 0.f), 1023.f);
  float y1 = fminf(fmaxf(cy - 0.5f * ph, 0.f), 1023.f);
  float x2 = fminf(fmaxf(cx + 0.5f * pw, 0.f), 1023.f);
  float y2 = fminf(fmaxf(cy + 0.5f * ph, 0.f), 1023.f);

  const long o = ((long)b * 5120 + pos * 5 + a) * 5;
  out[o + 0] = x1;
  out[o + 1] = y1;
  out[o + 2] = x2;
  out[o + 3] = y2;
  out[o + 4] = score;
  out[819200 + (long)b * 5120 + pos * 5 + a] = (float)arg;
}

// ---------------------------------------------------------------------------
// workspace layout (bytes):
//   0          fph  [32][34][34][512] f16   37,879,808
//   37879808   fpl                          37,879,808
//   75759616   A1h  [1024][4608] f16         9,437,184
//   85196800   A1l                           9,437,184
//   94633984   A2h  [512][1024] f16          1,048,576
//   95682560   A2l                           1,048,576
//   96731136   scale f32[1024]                   4,096
//   96735232   shift f32[1024]                   4,096
//   96739328   bias  f32[512]                    2,048
//   96741376   xth  [32768][1024] f16       67,108,864
//   163850240  xtl                          67,108,864
//   total 230,959,104;  preds f32[32768][512] aliases offset 0
// ---------------------------------------------------------------------------
extern "C" void kernel_launch(void* const* d_in, const int* in_sizes, int n_in,
                              void* d_out, int out_size, void* d_ws, size_t ws_size,
                              hipStream_t stream) {
  (void)in_sizes; (void)n_in; (void)out_size; (void)ws_size;
  const float* features = (const float*)d_in[0];
  const float* conv1_w = (const float*)d_in[1];
  const float* bn_g = (const float*)d_in[2];
  const float* bn_b = (const float*)d_in[3];
  const float* bn_m = (const float*)d_in[4];
  const float* bn_v = (const float*)d_in[5];
  const float* conv2_w = (const float*)d_in[6];
  const float* conv2_b = (const float*)d_in[7];
  float* out = (float*)d_out;
  char* ws = (char*)d_ws;

  f16* fph = (f16*)(ws + 0);
  f16* fpl = (f16*)(ws + 37879808L);
  f16* A1h = (f16*)(ws + 75759616L);
  f16* A1l = (f16*)(ws + 85196800L);
  f16* A2h = (f16*)(ws + 94633984L);
  f16* A2l = (f16*)(ws + 95682560L);
  float* scale = (float*)(ws + 96731136L);
  float* shift = (float*)(ws + 96735232L);
  float* bias = (float*)(ws + 96739328L);
  f16* xth = (f16*)(ws + 96741376L);
  f16* xtl = (f16*)(ws + 163850240L);
  float* preds = (float*)(ws + 0);  // alias: fp dead after gemm1

  ring_zero<<<dim3(132, 32), 64, 0, stream>>>(fph, fpl);
  prep_misc<<<1, 1024, 0, stream>>>(bn_g, bn_b, bn_m, bn_v, conv2_b, scale, shift, bias);
  prep_w1<<<dim3(1024, 18), 256, 0, stream>>>(conv1_w, A1h, A1l);
  prep_w2<<<dim3(512, 4), 256, 0, stream>>>(conv2_w, A2h, A2l);
  prep_feat<<<dim3(32, 32), 256, 0, stream>>>(features, fph, fpl);
  gemm1<<<dim3(128, 4), 512, 0, stream>>>(A1h, A1l, fph, fpl, scale, shift, xth, xtl);
  gemm2<<<dim3(128, 2), 512, 0, stream>>>(A2h, A2l, xth, xtl, bias, preds);
  decode<<<640, 256, 0, stream>>>(preds, out);
}